// Round 3
// baseline (116.350 us; speedup 1.0000x reference)
//
#include <hip/hip_runtime.h>

// out[r][c] = (float)weight[r][c] * scale[r]
// weight: int32 container holding int8 values, shape (8192, 8192)
// scale:  f32, shape (8192, 1)
// out:    f32, shape (8192, 8192)
//
// Memory-bound streaming: 256 MB read + 256 MB write, zero reuse.
// - 16 B/lane coalesced access via clang ext_vector types (the nontemporal
//   builtins reject HIP_vector_type structs like int4/float4)
// - 4x unrolled grid-stride loop: 4 independent loads in flight per thread
// - non-temporal load/store (nt) to avoid wasting L2/L3 retention on a
//   512 MB stream that exceeds the 256 MiB Infinity Cache

typedef int   iv4 __attribute__((ext_vector_type(4)));
typedef float fv4 __attribute__((ext_vector_type(4)));

__global__ __launch_bounds__(256) void decompress_int8_sym_kernel(
    const iv4* __restrict__ w4,
    const float* __restrict__ scale,
    fv4* __restrict__ out4,
    int n4,           // total 4-wide groups = OUT*IN/4
    int row_shift)    // log2(IN/4)
{
    int tid = blockIdx.x * blockDim.x + threadIdx.x;
    int stride = gridDim.x * blockDim.x;

    int i = tid;
    // Main loop, unrolled x4 (independent iterations -> 4 outstanding loads)
    for (; i + 3 * stride < n4; i += 4 * stride) {
        int i0 = i;
        int i1 = i + stride;
        int i2 = i + 2 * stride;
        int i3 = i + 3 * stride;

        iv4 v0 = __builtin_nontemporal_load(&w4[i0]);
        iv4 v1 = __builtin_nontemporal_load(&w4[i1]);
        iv4 v2 = __builtin_nontemporal_load(&w4[i2]);
        iv4 v3 = __builtin_nontemporal_load(&w4[i3]);

        float s0 = scale[i0 >> row_shift];
        float s1 = scale[i1 >> row_shift];
        float s2 = scale[i2 >> row_shift];
        float s3 = scale[i3 >> row_shift];

        fv4 o0, o1, o2, o3;
        o0.x = (float)v0.x * s0; o0.y = (float)v0.y * s0;
        o0.z = (float)v0.z * s0; o0.w = (float)v0.w * s0;
        o1.x = (float)v1.x * s1; o1.y = (float)v1.y * s1;
        o1.z = (float)v1.z * s1; o1.w = (float)v1.w * s1;
        o2.x = (float)v2.x * s2; o2.y = (float)v2.y * s2;
        o2.z = (float)v2.z * s2; o2.w = (float)v2.w * s2;
        o3.x = (float)v3.x * s3; o3.y = (float)v3.y * s3;
        o3.z = (float)v3.z * s3; o3.w = (float)v3.w * s3;

        __builtin_nontemporal_store(o0, &out4[i0]);
        __builtin_nontemporal_store(o1, &out4[i1]);
        __builtin_nontemporal_store(o2, &out4[i2]);
        __builtin_nontemporal_store(o3, &out4[i3]);
    }
    // Tail
    for (; i < n4; i += stride) {
        iv4 v = __builtin_nontemporal_load(&w4[i]);
        float s = scale[i >> row_shift];
        fv4 o;
        o.x = (float)v.x * s;
        o.y = (float)v.y * s;
        o.z = (float)v.z * s;
        o.w = (float)v.w * s;
        __builtin_nontemporal_store(o, &out4[i]);
    }
}

extern "C" void kernel_launch(void* const* d_in, const int* in_sizes, int n_in,
                              void* d_out, int out_size, void* d_ws, size_t ws_size,
                              hipStream_t stream) {
    const iv4* w4 = (const iv4*)d_in[0];         // int32 weights, vectorized x4
    const float* scale = (const float*)d_in[1];  // per-row scales
    fv4* out4 = (fv4*)d_out;

    const int n_weights = in_sizes[0];           // OUT * IN
    const int n_rows    = in_sizes[1];           // OUT
    const int in_per_row = n_weights / n_rows;   // IN
    const int groups_per_row = in_per_row / 4;   // IN/4 (power of two here)
    const int row_shift = __builtin_ctz(groups_per_row);
    const int n4 = n_weights / 4;

    const int block = 256;
    int grid = (n4 + block - 1) / block;
    const int max_grid = 2048;                   // 256 CU x 8 blocks = max-occupancy fill
    if (grid > max_grid) grid = max_grid;

    decompress_int8_sym_kernel<<<grid, block, 0, stream>>>(w4, scale, out4, n4, row_shift);
}

// Round 4
// 99.807 us; speedup vs baseline: 1.1657x; 1.1657x over previous
//
#include <hip/hip_runtime.h>

// out[r][c] = (float)weight[r][c] * scale[r]
// weight: int32 container holding int8 values, shape (8192, 8192)
// scale:  f32, shape (8192, 1)
// out:    f32, shape (8192, 8192)
//
// Memory-bound streaming: 256 MB read + 256 MB write, zero reuse.
// R2 post-mortem: grid-stride 4x unroll + nt hints REGRESSED (116 vs 109 us)
// -- the 8 MB inter-load stride per thread killed DRAM page locality.
// R3: block-contiguous 4x unroll -- each block streams a sequential 16 KB
// chunk per iteration (4 coalesced wave loads at +0/+4/+8/+12 KB), plain
// cached loads/stores (revert nt).

typedef int   iv4 __attribute__((ext_vector_type(4)));
typedef float fv4 __attribute__((ext_vector_type(4)));

#define BLOCK 256
#define UNROLL 4
#define CHUNK (BLOCK * UNROLL)   // int4-groups per block-iteration (= 16 KB)

__global__ __launch_bounds__(BLOCK) void decompress_int8_sym_kernel(
    const iv4* __restrict__ w4,
    const float* __restrict__ scale,
    fv4* __restrict__ out4,
    int n4,           // total 4-wide groups = OUT*IN/4
    int row_shift)    // log2(IN/4)
{
    const int tid = threadIdx.x;
    const int bstride = gridDim.x * CHUNK;
    const int nfull = n4 / CHUNK;            // number of full chunks

    // Full chunks, block-contiguous
    for (long long c = blockIdx.x; c < nfull; c += gridDim.x) {
        int base = (int)(c * CHUNK);
        int i0 = base + tid;
        int i1 = i0 + BLOCK;
        int i2 = i0 + 2 * BLOCK;
        int i3 = i0 + 3 * BLOCK;

        iv4 v0 = w4[i0];
        iv4 v1 = w4[i1];
        iv4 v2 = w4[i2];
        iv4 v3 = w4[i3];

        float s0 = scale[i0 >> row_shift];
        float s1 = scale[i1 >> row_shift];
        float s2 = scale[i2 >> row_shift];
        float s3 = scale[i3 >> row_shift];

        fv4 o0, o1, o2, o3;
        o0.x = (float)v0.x * s0; o0.y = (float)v0.y * s0;
        o0.z = (float)v0.z * s0; o0.w = (float)v0.w * s0;
        o1.x = (float)v1.x * s1; o1.y = (float)v1.y * s1;
        o1.z = (float)v1.z * s1; o1.w = (float)v1.w * s1;
        o2.x = (float)v2.x * s2; o2.y = (float)v2.y * s2;
        o2.z = (float)v2.z * s2; o2.w = (float)v2.w * s2;
        o3.x = (float)v3.x * s3; o3.y = (float)v3.y * s3;
        o3.z = (float)v3.z * s3; o3.w = (float)v3.w * s3;

        out4[i0] = o0;
        out4[i1] = o1;
        out4[i2] = o2;
        out4[i3] = o3;
    }

    // Tail (n4 % CHUNK elements) -- handled by block 0
    if (blockIdx.x == 0) {
        for (int i = nfull * CHUNK + tid; i < n4; i += BLOCK) {
            iv4 v = w4[i];
            float s = scale[i >> row_shift];
            fv4 o;
            o.x = (float)v.x * s;
            o.y = (float)v.y * s;
            o.z = (float)v.z * s;
            o.w = (float)v.w * s;
            out4[i] = o;
        }
    }
}

extern "C" void kernel_launch(void* const* d_in, const int* in_sizes, int n_in,
                              void* d_out, int out_size, void* d_ws, size_t ws_size,
                              hipStream_t stream) {
    const iv4* w4 = (const iv4*)d_in[0];         // int32 weights, vectorized x4
    const float* scale = (const float*)d_in[1];  // per-row scales
    fv4* out4 = (fv4*)d_out;

    const int n_weights = in_sizes[0];           // OUT * IN
    const int n_rows    = in_sizes[1];           // OUT
    const int in_per_row = n_weights / n_rows;   // IN
    const int groups_per_row = in_per_row / 4;   // IN/4 (power of two here)
    const int row_shift = __builtin_ctz(groups_per_row);
    const int n4 = n_weights / 4;

    int grid = (n4 + CHUNK - 1) / CHUNK;
    const int max_grid = 2048;                   // 256 CU x 8 blocks = full occupancy
    if (grid > max_grid) grid = max_grid;

    decompress_int8_sym_kernel<<<grid, BLOCK, 0, stream>>>(w4, scale, out4, n4, row_shift);
}